// Round 6
// baseline (80444.037 us; speedup 1.0000x reference)
//
#include <hip/hip_runtime.h>
#include <hip/hip_cooperative_groups.h>
#include <math.h>

namespace cg = cooperative_groups;
#define TMAX 200

__device__ __forceinline__ float sig_(float x){ return 1.0f/(1.0f+expf(-x)); }

// ws (k-major): xT[256][512] ; hT[1024][512] ; haT[2048][512]  (6.8 MB)
// Persistent cooperative kernel, grid-size-agnostic (units strided by gridDim.x).
// Units: A = 512 (64 jg x 8 bg), B = 512 (64 ng x 8 bg), C = 256 (32 cg x 8 bg).
// LDS: stage[4096]f + aux[2048]f + tables = ~26 KB  (< round-3's proven 34.8 KB).

__global__ __launch_bounds__(256, 2)
void kfused(const int* __restrict__ lengths,
            const float* __restrict__ eps,
            const float* __restrict__ W_ih, const float* __restrict__ b_ih,
            const float* __restrict__ b_hh,
            const float* __restrict__ W1a, const float* __restrict__ b1a,
            const float* __restrict__ W1b, const float* __restrict__ b1b,
            const float* __restrict__ W2a, const float* __restrict__ b2a,
            const float* __restrict__ W2b, const float* __restrict__ b2b,
            float* __restrict__ out_p1, float* __restrict__ out_p2, float* __restrict__ out_h,
            float* __restrict__ xT, float* __restrict__ hT, float* __restrict__ haT)
{
    __shared__ float stage[4096];
    __shared__ float aux[2048];
    __shared__ int sbs[TMAX], soff[TMAX];

    const int tid = threadIdx.x;
    const int bid = blockIdx.x;
    const int grd = gridDim.x;
    const int wv  = __builtin_amdgcn_readfirstlane(tid >> 6);   // 0..3
    const int l   = tid & 63;

    if (tid < TMAX) {
        int c = 0;
        for (int b = 0; b < 512; ++b) c += (lengths[b] > tid) ? 1 : 0;
        sbs[tid] = c;
    }
    __syncthreads();
    if (tid == 0) { int a = 0; for (int i = 0; i < TMAX; ++i) { soff[i] = a; a += sbs[i]; } }
    __syncthreads();

    cg::grid_group grid = cg::this_grid();

    for (int t = 0; t < TMAX; ++t) {
        const int bsz = sbs[t], ofs = soff[t];

        // ================= phase A: gi = x@W_ih^T -> GRU -> h =================
        for (int u = bid; u < 512; u += grd) {
            const int jg = u >> 3, bg = u & 7;
            const int bb = bg * 64, j0 = jg * 16;
            float accR[4] = {0.f,0.f,0.f,0.f};
            float accZ[4] = {0.f,0.f,0.f,0.f};
            float accN[4] = {0.f,0.f,0.f,0.f};
            if (t > 0) {
                float4 pf[4];
                #pragma unroll
                for (int i = 0; i < 4; ++i) {
                    const int idx = tid + i * 256;
                    pf[i] = *(const float4*)&xT[(size_t)(idx >> 4) * 512 + bb + (idx & 15) * 4];
                }
                #pragma unroll
                for (int i = 0; i < 4; ++i) {
                    const int idx = tid + i * 256;
                    *(float4*)&stage[(idx >> 4) * 64 + (idx & 15) * 4] = pf[i];
                }
                __syncthreads();
                for (int ch = 0; ch < 4; ++ch) {
                    const int k0 = ch * 64;
                    if (ch < 3) {
                        #pragma unroll
                        for (int i = 0; i < 4; ++i) {
                            const int idx = tid + i * 256;
                            pf[i] = *(const float4*)&xT[(size_t)(k0 + 64 + (idx >> 4)) * 512 + bb + (idx & 15) * 4];
                        }
                    }
                    #pragma unroll 4
                    for (int k4 = 0; k4 < 16; ++k4) {
                        const int kk = k4 * 4;
                        const float x0 = stage[(kk+0)*64 + l];
                        const float x1 = stage[(kk+1)*64 + l];
                        const float x2 = stage[(kk+2)*64 + l];
                        const float x3 = stage[(kk+3)*64 + l];
                        #pragma unroll
                        for (int q = 0; q < 4; ++q) {
                            const int jr = j0 + wv * 4 + q;
                            const float4 wr = *(const float4*)&W_ih[(size_t)jr * 256 + k0 + kk];
                            const float4 wz = *(const float4*)&W_ih[(size_t)(1024 + jr) * 256 + k0 + kk];
                            const float4 wn = *(const float4*)&W_ih[(size_t)(2048 + jr) * 256 + k0 + kk];
                            accR[q] = fmaf(x0,wr.x,fmaf(x1,wr.y,fmaf(x2,wr.z,fmaf(x3,wr.w,accR[q]))));
                            accZ[q] = fmaf(x0,wz.x,fmaf(x1,wz.y,fmaf(x2,wz.z,fmaf(x3,wz.w,accZ[q]))));
                            accN[q] = fmaf(x0,wn.x,fmaf(x1,wn.y,fmaf(x2,wn.z,fmaf(x3,wn.w,accN[q]))));
                        }
                    }
                    __syncthreads();
                    if (ch < 3) {
                        #pragma unroll
                        for (int i = 0; i < 4; ++i) {
                            const int idx = tid + i * 256;
                            *(float4*)&stage[(idx >> 4) * 64 + (idx & 15) * 4] = pf[i];
                        }
                        __syncthreads();
                    }
                }
            }
            #pragma unroll
            for (int q = 0; q < 4; ++q) {
                const int jr = j0 + wv * 4 + q;
                const float r = sig_(accR[q] + b_ih[jr] + b_hh[jr]);
                const float z = sig_(accZ[q] + b_ih[1024 + jr] + b_hh[1024 + jr]);
                const float n = tanhf(accN[q] + b_ih[2048 + jr] + r * b_hh[2048 + jr]);
                const float h = (1.f - z) * n;
                hT[(size_t)jr * 512 + bb + l] = h;
                aux[(wv * 4 + q) * 64 + l] = h;
            }
            __syncthreads();
            {
                const int b = tid >> 2, jj = (tid & 3) * 4;
                const int bglob = bb + b;
                if (bglob < bsz) {
                    float4 v = { aux[(jj+0)*64 + b], aux[(jj+1)*64 + b],
                                 aux[(jj+2)*64 + b], aux[(jj+3)*64 + b] };
                    *(float4*)&out_h[(size_t)(ofs + bglob) * 1024 + j0 + jj] = v;
                }
            }
            __syncthreads();
        }
        grid.sync();

        // ================= phase B: ha = tanh(h@Wa^T + ba) =================
        for (int u = bid; u < 512; u += grd) {
            const int ng = u >> 3, bg = u & 7;
            const int bb = bg * 64, n0 = ng * 32;
            const int fam = (n0 >= 1024) ? 1 : 0;
            const float* __restrict__ Wa = fam ? W2a : W1a;
            const float* __restrict__ ba = fam ? b2a : b1a;
            const int nr0 = n0 - fam * 1024 + wv * 8;
            float acc[8] = {0.f,0.f,0.f,0.f,0.f,0.f,0.f,0.f};
            float4 pf[4];
            #pragma unroll
            for (int i = 0; i < 4; ++i) {
                const int idx = tid + i * 256;
                pf[i] = *(const float4*)&hT[(size_t)(idx >> 4) * 512 + bb + (idx & 15) * 4];
            }
            #pragma unroll
            for (int i = 0; i < 4; ++i) {
                const int idx = tid + i * 256;
                *(float4*)&stage[(idx >> 4) * 64 + (idx & 15) * 4] = pf[i];
            }
            __syncthreads();
            for (int ch = 0; ch < 16; ++ch) {
                const int k0 = ch * 64;
                if (ch < 15) {
                    #pragma unroll
                    for (int i = 0; i < 4; ++i) {
                        const int idx = tid + i * 256;
                        pf[i] = *(const float4*)&hT[(size_t)(k0 + 64 + (idx >> 4)) * 512 + bb + (idx & 15) * 4];
                    }
                }
                #pragma unroll 4
                for (int k4 = 0; k4 < 16; ++k4) {
                    const int kk = k4 * 4;
                    const float x0 = stage[(kk+0)*64 + l];
                    const float x1 = stage[(kk+1)*64 + l];
                    const float x2 = stage[(kk+2)*64 + l];
                    const float x3 = stage[(kk+3)*64 + l];
                    #pragma unroll
                    for (int c = 0; c < 8; ++c) {
                        const float4 w = *(const float4*)&Wa[(size_t)(nr0 + c) * 1024 + k0 + kk];
                        acc[c] = fmaf(x0,w.x,fmaf(x1,w.y,fmaf(x2,w.z,fmaf(x3,w.w,acc[c]))));
                    }
                }
                __syncthreads();
                if (ch < 15) {
                    #pragma unroll
                    for (int i = 0; i < 4; ++i) {
                        const int idx = tid + i * 256;
                        *(float4*)&stage[(idx >> 4) * 64 + (idx & 15) * 4] = pf[i];
                    }
                    __syncthreads();
                }
            }
            #pragma unroll
            for (int c = 0; c < 8; ++c)
                haT[(size_t)(n0 + wv * 8 + c) * 512 + bb + l] = tanhf(acc[c] + ba[nr0 + c]);
            __syncthreads();
        }
        grid.sync();

        // ====== phase C: p = ha@Wb^T + bb; scatter p; x_{t+1} = p1+exp(.5 p2)*eps[t] ======
        for (int u = bid; u < 256; u += grd) {
            const int cgi = u >> 3, bg = u & 7;
            const int bb = bg * 64, c0 = cgi * 8;
            const int famC = wv >> 1, khC = wv & 1;
            const float* __restrict__ Wb = famC ? W2b : W1b;
            float acc[8] = {0.f,0.f,0.f,0.f,0.f,0.f,0.f,0.f};
            float4 pf[4];
            #pragma unroll
            for (int i = 0; i < 4; ++i) {
                const int idx = tid + i * 256;
                const int w = idx >> 8, rem = idx & 255;
                const int rg = (w >> 1) * 1024 + (w & 1) * 512 + (rem >> 4);
                pf[i] = *(const float4*)&haT[(size_t)rg * 512 + bb + (rem & 15) * 4];
            }
            #pragma unroll
            for (int i = 0; i < 4; ++i) {
                const int idx = tid + i * 256;
                const int w = idx >> 8, rem = idx & 255;
                *(float4*)&stage[w * 1024 + (rem >> 4) * 64 + (rem & 15) * 4] = pf[i];
            }
            __syncthreads();
            for (int ch = 0; ch < 32; ++ch) {
                if (ch < 31) {
                    #pragma unroll
                    for (int i = 0; i < 4; ++i) {
                        const int idx = tid + i * 256;
                        const int w = idx >> 8, rem = idx & 255;
                        const int rg = (w >> 1) * 1024 + (w & 1) * 512 + (ch + 1) * 16 + (rem >> 4);
                        pf[i] = *(const float4*)&haT[(size_t)rg * 512 + bb + (rem & 15) * 4];
                    }
                }
                const int kb = khC * 512 + ch * 16;
                #pragma unroll
                for (int k4 = 0; k4 < 4; ++k4) {
                    const int kk = k4 * 4;
                    const float v0 = stage[wv * 1024 + (kk+0)*64 + l];
                    const float v1 = stage[wv * 1024 + (kk+1)*64 + l];
                    const float v2 = stage[wv * 1024 + (kk+2)*64 + l];
                    const float v3 = stage[wv * 1024 + (kk+3)*64 + l];
                    #pragma unroll
                    for (int c = 0; c < 8; ++c) {
                        const float4 w4 = *(const float4*)&Wb[(size_t)(c0 + c) * 1024 + kb + kk];
                        acc[c] = fmaf(v0,w4.x,fmaf(v1,w4.y,fmaf(v2,w4.z,fmaf(v3,w4.w,acc[c]))));
                    }
                }
                __syncthreads();
                if (ch < 31) {
                    #pragma unroll
                    for (int i = 0; i < 4; ++i) {
                        const int idx = tid + i * 256;
                        const int w = idx >> 8, rem = idx & 255;
                        *(float4*)&stage[w * 1024 + (rem >> 4) * 64 + (rem & 15) * 4] = pf[i];
                    }
                    __syncthreads();
                }
            }
            // deterministic cross-wave reduce (k-halves per family)
            #pragma unroll
            for (int c = 0; c < 8; ++c) aux[wv * 512 + c * 64 + l] = acc[c];
            __syncthreads();
            float p1s[2], p2s[2];
            #pragma unroll
            for (int p = 0; p < 2; ++p) {
                const int linear = p * 256 + tid, c = linear >> 6, b = linear & 63;
                p1s[p] = aux[0*512 + c*64 + b] + aux[1*512 + c*64 + b] + b1b[c0 + c];
                p2s[p] = aux[2*512 + c*64 + b] + aux[3*512 + c*64 + b] + b2b[c0 + c];
            }
            __syncthreads();
            #pragma unroll
            for (int p = 0; p < 2; ++p) {
                const int linear = p * 256 + tid, c = linear >> 6, b = linear & 63;
                aux[b * 8 + c] = p1s[p];
                aux[512 + b * 8 + c] = p2s[p];
            }
            __syncthreads();
            {
                const int b = tid >> 2, sub = tid & 3;
                const int fam2 = sub >> 1, chh = sub & 1;
                const int bglob = bb + b;
                const float4 v = *(const float4*)&aux[fam2 * 512 + b * 8 + chh * 4];
                if (bglob < bsz) {
                    float* __restrict__ dst = fam2 ? out_p2 : out_p1;
                    *(float4*)&dst[(size_t)(ofs + bglob) * 256 + c0 + chh * 4] = v;
                }
                if (fam2 == 0) {
                    const float4 p2v = *(const float4*)&aux[512 + b * 8 + chh * 4];
                    const float4 e = *(const float4*)&eps[(size_t)t * 131072 + (size_t)bglob * 256 + c0 + chh * 4];
                    xT[(size_t)(c0 + chh*4 + 0) * 512 + bglob] = fmaf(expf(0.5f * p2v.x), e.x, v.x);
                    xT[(size_t)(c0 + chh*4 + 1) * 512 + bglob] = fmaf(expf(0.5f * p2v.y), e.y, v.y);
                    xT[(size_t)(c0 + chh*4 + 2) * 512 + bglob] = fmaf(expf(0.5f * p2v.z), e.z, v.z);
                    xT[(size_t)(c0 + chh*4 + 3) * 512 + bglob] = fmaf(expf(0.5f * p2v.w), e.w, v.w);
                }
            }
            __syncthreads();
        }
        grid.sync();
    }
}

extern "C" void kernel_launch(void* const* d_in, const int* in_sizes, int n_in,
                              void* d_out, int out_size, void* d_ws, size_t ws_size,
                              hipStream_t stream)
{
    (void)in_sizes; (void)n_in; (void)ws_size;
    const int*   lengths = (const int*)  d_in[1];
    const float* eps     = (const float*)d_in[2];
    const float* W_ih    = (const float*)d_in[5];
    const float* b_ih    = (const float*)d_in[6];
    const float* b_hh    = (const float*)d_in[8];
    const float* W1a     = (const float*)d_in[9];
    const float* b1a     = (const float*)d_in[10];
    const float* W1b     = (const float*)d_in[11];
    const float* b1b     = (const float*)d_in[12];
    const float* W2a     = (const float*)d_in[13];
    const float* b2a     = (const float*)d_in[14];
    const float* W2b     = (const float*)d_in[15];
    const float* b2b     = (const float*)d_in[16];

    float* out = (float*)d_out;
    const size_t N = (size_t)out_size / 1536;
    float* out_p1 = out;
    float* out_p2 = out + N * 256;
    float* out_h  = out + N * 512;

    float* xT  = (float*)d_ws;          // [256][512]
    float* hT  = xT + 131072;           // [1024][512]
    float* haT = hT + 524288;           // [2048][512]   total 6.8 MB

    // Size the grid to what the RUNTIME says can be co-resident (launch cannot fail).
    int dev = 0;
    (void)hipGetDevice(&dev);
    int ncu = 0;
    if (hipDeviceGetAttribute(&ncu, hipDeviceAttributeMultiprocessorCount, dev) != hipSuccess || ncu <= 0)
        ncu = 256;
    int maxB = 0;
    if (hipOccupancyMaxActiveBlocksPerMultiprocessor(&maxB, (const void*)kfused, 256, 0) != hipSuccess || maxB <= 0)
        maxB = 1;
    long cap = (long)maxB * (long)ncu;
    int grd = (cap < 512) ? (int)cap : 512;
    if (grd < 1) grd = 1;

    void* args[] = {
        (void*)&lengths, (void*)&eps, (void*)&W_ih, (void*)&b_ih, (void*)&b_hh,
        (void*)&W1a, (void*)&b1a, (void*)&W1b, (void*)&b1b,
        (void*)&W2a, (void*)&b2a, (void*)&W2b, (void*)&b2b,
        (void*)&out_p1, (void*)&out_p2, (void*)&out_h,
        (void*)&xT, (void*)&hT, (void*)&haT
    };
    hipLaunchCooperativeKernel((void*)kfused, dim3(grd), dim3(256), args, 0, stream);
}